// Round 6
// baseline (258.922 us; speedup 1.0000x reference)
//
#include <hip/hip_runtime.h>

// Chamfer distance, B=8, N=M=8192, D=3, fp32 — R17: TWO-DISPATCH version.
// R12/R15 main structure (the 44us plateau config) + in-kernel final
// reduction (threadfence-reduction pattern) -> removes final kernel AND
// memset dispatch. pack zeroes out + flags each replay.
//
// dist[i][j] = nx_i + ny_j - 2 x_i.y_j; out = mean(min_j) + mean(min_i).
// K=16 bf16-split packing (validated R8-R16, absmax 0.0):
//   A row = [ah0 ah1 ah2 ah0 ah1 ah2 al0 al1 | al2 nxh nxl 1 1 0 0 0]
//   B col = [yh0 yh1 yh2 yl0 yl1 yl2 yh0 yh1 | yh2 1 1 nyh nyl 0 0 0]
//
// R11-R16 post-mortem: main invariant at ~44us across 4 different schedules
// (compiler re-serializes; MfmaUtil*dur == MFMA floor every time), but bench
// total stuck at ~95-114us: ~50us is non-main (pack/final/memset dispatches
// + graph gaps). R17 attacks dispatch count: 4 ops -> 2 ops.

#define B_ 8
#define N_ 8192
#define PTS (B_ * N_)            // 65536 points per cloud
#define ROWS_TOTAL (2 * PTS)     // 131072 row-min slots (both directions)
#define NTILES 2048              // 32-point tiles per cloud (65536/32)
#define NRG 512                  // row-groups of 256 rows (both directions)
#define TPB 256

typedef short bf16x8 __attribute__((ext_vector_type(8)));
typedef float f32x16 __attribute__((ext_vector_type(16)));

__device__ __forceinline__ unsigned b16(float f) {   // fp32 -> bf16 bits (RNE)
  unsigned u = __float_as_uint(f);
  return (u + 0x7FFFu + ((u >> 16) & 1u)) >> 16;
}
__device__ __forceinline__ float bf(unsigned h) { return __uint_as_float(h << 16); }

__device__ __forceinline__ float devload(const float* p) {   // agent-scope load
  return __hip_atomic_load(p, __ATOMIC_RELAXED, __HIP_MEMORY_SCOPE_AGENT);
}

// ---- dispatch 1: fragment packing + zero out/flags (replaces memset) ----
__global__ __launch_bounds__(256) void pack_frags_k(
    const float* __restrict__ x, const float* __restrict__ y,
    uint4* __restrict__ afrag, uint4* __restrict__ bfrag,
    int* __restrict__ flags, float* __restrict__ out) {
  const unsigned one = 0x3F80u;
  int t = blockIdx.x * 256 + threadIdx.x;   // 0 .. 262143
  if (t < NRG) flags[t] = 0;                 // re-arm completion flags
  if (t == 0) *out = 0.0f;                   // re-arm output accumulator
  int kind = t >> 17;                        // 0 = A-frag, 1 = B-frag
  int dir = (t >> 16) & 1;                   // 0: rows=x scan y; 1: rows=y scan x
  int p = t & 65535;
  int tile = dir * NTILES + (p >> 5), m = p & 31;
  if (kind == 0) {
    const float* src = dir ? y : x;          // row ("own") cloud
    const float* po = src + 3 * p;
    float v0 = po[0], v1 = po[1], v2 = po[2];
    float nv = fmaf(v0, v0, fmaf(v1, v1, v2 * v2));
    float a0 = -2.0f * v0, a1 = -2.0f * v1, a2 = -2.0f * v2;
    unsigned ah0 = b16(a0), ah1 = b16(a1), ah2 = b16(a2);
    unsigned al0 = b16(a0 - bf(ah0)), al1 = b16(a1 - bf(ah1)), al2 = b16(a2 - bf(ah2));
    unsigned nh = b16(nv), nl = b16(nv - bf(nh));
    afrag[tile * 64 + m]      = make_uint4(ah0 | (ah1 << 16), ah2 | (ah0 << 16),
                                           ah1 | (ah2 << 16), al0 | (al1 << 16));
    afrag[tile * 64 + 32 + m] = make_uint4(al2 | (nh << 16), nl | (one << 16), one, 0u);
  } else {
    const float* src = dir ? x : y;          // candidate cloud
    const float* pc = src + 3 * p;
    float c0 = pc[0], c1 = pc[1], c2 = pc[2];
    float nc = fmaf(c0, c0, fmaf(c1, c1, c2 * c2));
    unsigned yh0 = b16(c0), yh1 = b16(c1), yh2 = b16(c2);
    unsigned yl0 = b16(c0 - bf(yh0)), yl1 = b16(c1 - bf(yh1)), yl2 = b16(c2 - bf(yh2));
    unsigned nh = b16(nc), nl = b16(nc - bf(nh));
    bfrag[tile * 64 + m]      = make_uint4(yh0 | (yh1 << 16), yh2 | (yl0 << 16),
                                           yl1 | (yl2 << 16), yh0 | (yh1 << 16));
    bfrag[tile * 64 + 32 + m] = make_uint4(yh2 | (one << 16), one | (nh << 16), nl, 0u);
  }
}

// ---- dispatch 2: main + in-kernel final reduction ----
// 2048 blocks x 256 thr; block = 4 waves x 64 rows = 256 rows, scans one
// candidate quarter (2048 cands = 64 prepacked tiles). 4th finisher of each
// row-group merges the 4 quarter slabs and atomicAdds the partial mean.
__global__ __launch_bounds__(TPB, 3) void chamfer_main_k(
    const uint4* __restrict__ afrag, const uint4* __restrict__ bfrag,
    float* __restrict__ gpart, int* __restrict__ flags,
    float* __restrict__ out) {
  __shared__ int doMerge;
  __shared__ float red[4];

  int t = threadIdx.x, lane = t & 63, w = t >> 6;    // 4 waves
  int b0 = blockIdx.x;
  // XCD-bijective swizzle (2048 blocks % 8 == 0): each XCD gets 256
  // consecutive effective ids = 2 full (dir,batch) families -> small L2 set.
  int eff = ((b0 & 7) << 8) | (b0 >> 3);
  int q = eff & 3;                 // candidate quarter (64 B-tiles)
  int rg = eff >> 2;               // 0..511 : 256-row groups
  int dir = rg >> 8;
  int batch = (rg >> 5) & 7;
  int rb = rg & 31;                // 256-row block within batch

  // A-frags: 2 row-tiles (64 rows) per wave, straight from prepacked global.
  int tileA0 = dir * NTILES + batch * 256 + rb * 8 + w * 2;
  bf16x8 A0 = __builtin_bit_cast(bf16x8, afrag[tileA0 * 64 + lane]);
  bf16x8 A1 = __builtin_bit_cast(bf16x8, afrag[(tileA0 + 1) * 64 + lane]);

  const uint4* bt = bfrag + (size_t)(dir * NTILES + batch * 256 + q * 64) * 64 + lane;

  f32x16 z, rm0, rm1;
#pragma unroll
  for (int r = 0; r < 16; ++r) { z[r] = 0.0f; rm0[r] = 1e30f; rm1[r] = 1e30f; }

#define LD(ti) __builtin_bit_cast(bf16x8, bt[(ti) * 64])
#define MF(Aa, Bb) __builtin_amdgcn_mfma_f32_32x32x16_bf16(Aa, Bb, z, 0, 0, 0)

#pragma unroll 2
  for (int j = 0; j < 64; j += 2) {          // 64 tiles, 2 per iter
    bf16x8 B0 = LD(j), B1 = LD(j + 1);
    f32x16 a0 = MF(A0, B0), a1 = MF(A1, B0);
    f32x16 a2 = MF(A0, B1), a3 = MF(A1, B1);
#pragma unroll
    for (int r = 0; r < 16; ++r) {
      rm0[r] = fminf(fminf(rm0[r], a0[r]), a2[r]);   // v_min3_f32
      rm1[r] = fminf(fminf(rm1[r], a1[r]), a3[r]);   // v_min3_f32
    }
  }
#undef LD
#undef MF

  // ---- epilogue: fold 32 cols per half (butterfly), store row-mins ----
#pragma unroll
  for (int msk = 1; msk <= 16; msk <<= 1)
#pragma unroll
    for (int r = 0; r < 16; ++r) {
      rm0[r] = fminf(rm0[r], __shfl_xor(rm0[r], msk, 64));
      rm1[r] = fminf(rm1[r], __shfl_xor(rm1[r], msk, 64));
    }

  int rgbase = dir * PTS + batch * N_ + rb * 256;    // row-group base row
  float* gp = gpart + (size_t)q * ROWS_TOTAL + rgbase + w * 64;
  if ((lane & 31) == 0) {                      // lanes 0 and 32 (h = lane>>5)
    int h = lane >> 5;
#pragma unroll
    for (int r = 0; r < 16; ++r) {
      int rr = (r & 3) + 8 * (r >> 2) + 4 * h;
      gp[rr] = rm0[r];
      gp[32 + rr] = rm1[r];
    }
  }

  // ---- threadfence reduction: 4th finisher of this row-group merges ----
  __threadfence();                             // release our slab device-wide
  if (t == 0)
    doMerge = (atomicAdd(&flags[rg], 1) == 3) ? 1 : 0;
  __syncthreads();
  if (doMerge) {
    __threadfence();                           // acquire partners' slabs
    int row = rgbase + t;                      // one row per thread (256 rows)
    float v0 = devload(gpart + 0 * (size_t)ROWS_TOTAL + row);
    float v1 = devload(gpart + 1 * (size_t)ROWS_TOTAL + row);
    float v2 = devload(gpart + 2 * (size_t)ROWS_TOTAL + row);
    float v3 = devload(gpart + 3 * (size_t)ROWS_TOTAL + row);
    float s = fminf(fminf(v0, v1), fminf(v2, v3));
    for (int off = 32; off > 0; off >>= 1) s += __shfl_down(s, off, 64);
    if (lane == 0) red[w] = s;
    __syncthreads();
    if (t == 0) {
      float tt = (red[0] + red[1]) + (red[2] + red[3]);
      atomicAdd(out, tt * (1.0f / (float)PTS));
    }
  }
}

extern "C" void kernel_launch(void* const* d_in, const int* in_sizes, int n_in,
                              void* d_out, int out_size, void* d_ws, size_t ws_size,
                              hipStream_t stream) {
  const float* x = (const float*)d_in[0];
  const float* y = (const float*)d_in[1];
  float* out = (float*)d_out;
  // ws layout: flags 4KB | gpart 2MB | afrag 4MB | bfrag 4MB  (~10MB total)
  int* flags = (int*)d_ws;
  float* gpart = (float*)((char*)d_ws + 4096);
  uint4* afrag = (uint4*)((char*)gpart + (size_t)4 * ROWS_TOTAL * sizeof(float));
  uint4* bfrag = afrag + (size_t)2 * NTILES * 64;

  pack_frags_k<<<1024, 256, 0, stream>>>(x, y, afrag, bfrag, flags, out);
  chamfer_main_k<<<2048, TPB, 0, stream>>>(afrag, bfrag, gpart, flags, out);
}

// Round 7
// 239.872 us; speedup vs baseline: 1.0794x; 1.0794x over previous
//
#include <hip/hip_runtime.h>

// Chamfer distance, B=8, N=M=8192, D=3, fp32 — R18: 4 A-tiles/wave
// (double arithmetic intensity per B-load), 3 dispatches, no fences.
//
// dist[i][j] = nx_i + ny_j - 2 x_i.y_j; out = mean(min_j) + mean(min_i).
// K=16 bf16-split packing (validated R8-R17, absmax 0.0):
//   A row = [ah0 ah1 ah2 ah0 ah1 ah2 al0 al1 | al2 nxh nxl 1 1 0 0 0]
//   B col = [yh0 yh1 yh2 yl0 yl1 yl2 yh0 yh1 | yh2 1 1 nyh nyl 0 0 0]
//
// R11-R17 post-mortem: (a) main invariant ~44us across 5 schedules — the
// per-step chain is 2 dependent L2 loads amortized over only 4 MFMA+32 min3;
// (b) bench total = sum(kernels) + ~50us FIXED (3/4/2-dispatch all show the
// same gap) -> minimize kernel-time sum; (c) device-scope fences in the hot
// kernel are poison (R17: 209us). R18: 4 A-tiles per wave -> 8 MFMA + 64
// min3 per 2 B-loads: same total work, half the steps, load latency paid
// half as often. pack zeroes out (memset dispatch dropped); plain final.

#define B_ 8
#define N_ 8192
#define PTS (B_ * N_)            // 65536 points per cloud
#define ROWS_TOTAL (2 * PTS)     // 131072 row-min slots (both directions)
#define NTILES 2048              // 32-point tiles per cloud (65536/32)
#define TPB 256

typedef short bf16x8 __attribute__((ext_vector_type(8)));
typedef float f32x16 __attribute__((ext_vector_type(16)));

__device__ __forceinline__ unsigned b16(float f) {   // fp32 -> bf16 bits (RNE)
  unsigned u = __float_as_uint(f);
  return (u + 0x7FFFu + ((u >> 16) & 1u)) >> 16;
}
__device__ __forceinline__ float bf(unsigned h) { return __uint_as_float(h << 16); }

// ---- dispatch 1: fragment packing + zero out (replaces memset) ----
__global__ __launch_bounds__(256) void pack_frags_k(
    const float* __restrict__ x, const float* __restrict__ y,
    uint4* __restrict__ afrag, uint4* __restrict__ bfrag,
    float* __restrict__ out) {
  const unsigned one = 0x3F80u;
  int t = blockIdx.x * 256 + threadIdx.x;   // 0 .. 262143
  if (t == 0) *out = 0.0f;                   // re-arm output accumulator
  int kind = t >> 17;                        // 0 = A-frag, 1 = B-frag
  int dir = (t >> 16) & 1;                   // 0: rows=x scan y; 1: rows=y scan x
  int p = t & 65535;
  int tile = dir * NTILES + (p >> 5), m = p & 31;
  if (kind == 0) {
    const float* src = dir ? y : x;          // row ("own") cloud
    const float* po = src + 3 * p;
    float v0 = po[0], v1 = po[1], v2 = po[2];
    float nv = fmaf(v0, v0, fmaf(v1, v1, v2 * v2));
    float a0 = -2.0f * v0, a1 = -2.0f * v1, a2 = -2.0f * v2;
    unsigned ah0 = b16(a0), ah1 = b16(a1), ah2 = b16(a2);
    unsigned al0 = b16(a0 - bf(ah0)), al1 = b16(a1 - bf(ah1)), al2 = b16(a2 - bf(ah2));
    unsigned nh = b16(nv), nl = b16(nv - bf(nh));
    afrag[tile * 64 + m]      = make_uint4(ah0 | (ah1 << 16), ah2 | (ah0 << 16),
                                           ah1 | (ah2 << 16), al0 | (al1 << 16));
    afrag[tile * 64 + 32 + m] = make_uint4(al2 | (nh << 16), nl | (one << 16), one, 0u);
  } else {
    const float* src = dir ? x : y;          // candidate cloud
    const float* pc = src + 3 * p;
    float c0 = pc[0], c1 = pc[1], c2 = pc[2];
    float nc = fmaf(c0, c0, fmaf(c1, c1, c2 * c2));
    unsigned yh0 = b16(c0), yh1 = b16(c1), yh2 = b16(c2);
    unsigned yl0 = b16(c0 - bf(yh0)), yl1 = b16(c1 - bf(yh1)), yl2 = b16(c2 - bf(yh2));
    unsigned nh = b16(nc), nl = b16(nc - bf(nh));
    bfrag[tile * 64 + m]      = make_uint4(yh0 | (yh1 << 16), yh2 | (yl0 << 16),
                                           yl1 | (yl2 << 16), yh0 | (yh1 << 16));
    bfrag[tile * 64 + 32 + m] = make_uint4(yh2 | (one << 16), one | (nh << 16), nl, 0u);
  }
}

// ---- dispatch 2: main. 1024 blocks x 256 thr; block = 4 waves x 128 rows
// = 512 rows, scans one candidate quarter (2048 cands = 64 tiles). ----
__global__ __launch_bounds__(TPB, 3) void chamfer_main_k(
    const uint4* __restrict__ afrag, const uint4* __restrict__ bfrag,
    float* __restrict__ gpart) {
  int t = threadIdx.x, lane = t & 63, w = t >> 6;    // 4 waves
  int b0 = blockIdx.x;
  // XCD-bijective swizzle (1024 blocks % 8 == 0): each XCD gets 128
  // consecutive effective ids -> shared (dir,batch) B-set, L2-resident.
  int eff = ((b0 & 7) << 7) | (b0 >> 3);
  int q = eff & 3;                 // candidate quarter (64 B-tiles)
  int rg = eff >> 2;               // 0..255 : 512-row groups
  int dir = rg >> 7;
  int batch = (rg >> 4) & 7;
  int rb = rg & 15;                // 512-row block within batch

  // A-frags: 4 row-tiles (128 rows) per wave, straight from prepacked global.
  int tileA0 = dir * NTILES + batch * 256 + rb * 16 + w * 4;
  bf16x8 A0 = __builtin_bit_cast(bf16x8, afrag[(tileA0 + 0) * 64 + lane]);
  bf16x8 A1 = __builtin_bit_cast(bf16x8, afrag[(tileA0 + 1) * 64 + lane]);
  bf16x8 A2 = __builtin_bit_cast(bf16x8, afrag[(tileA0 + 2) * 64 + lane]);
  bf16x8 A3 = __builtin_bit_cast(bf16x8, afrag[(tileA0 + 3) * 64 + lane]);

  const uint4* bt = bfrag + (size_t)(dir * NTILES + batch * 256 + q * 64) * 64 + lane;

  f32x16 z, rm0, rm1, rm2, rm3;
#pragma unroll
  for (int r = 0; r < 16; ++r) {
    z[r] = 0.0f;
    rm0[r] = 1e30f; rm1[r] = 1e30f; rm2[r] = 1e30f; rm3[r] = 1e30f;
  }

#define LD(ti) __builtin_bit_cast(bf16x8, bt[(ti) * 64])
#define MF(Aa, Bb) __builtin_amdgcn_mfma_f32_32x32x16_bf16(Aa, Bb, z, 0, 0, 0)

#pragma unroll 2
  for (int j = 0; j < 64; j += 2) {          // 64 tiles, 2 per iter
    bf16x8 B0 = LD(j), B1 = LD(j + 1);
    // 8 MFMAs per 2 loads: 2x the arithmetic intensity of R12-R15.
    f32x16 a00 = MF(A0, B0), a01 = MF(A0, B1);
    f32x16 a10 = MF(A1, B0), a11 = MF(A1, B1);
    f32x16 a20 = MF(A2, B0), a21 = MF(A2, B1);
    f32x16 a30 = MF(A3, B0), a31 = MF(A3, B1);
#pragma unroll
    for (int r = 0; r < 16; ++r) {
      rm0[r] = fminf(fminf(rm0[r], a00[r]), a01[r]);   // v_min3_f32
      rm1[r] = fminf(fminf(rm1[r], a10[r]), a11[r]);   // v_min3_f32
      rm2[r] = fminf(fminf(rm2[r], a20[r]), a21[r]);   // v_min3_f32
      rm3[r] = fminf(fminf(rm3[r], a30[r]), a31[r]);   // v_min3_f32
    }
  }
#undef LD
#undef MF

  // ---- epilogue: fold 32 cols per half (butterfly), store row-mins ----
#pragma unroll
  for (int msk = 1; msk <= 16; msk <<= 1)
#pragma unroll
    for (int r = 0; r < 16; ++r) {
      rm0[r] = fminf(rm0[r], __shfl_xor(rm0[r], msk, 64));
      rm1[r] = fminf(rm1[r], __shfl_xor(rm1[r], msk, 64));
      rm2[r] = fminf(rm2[r], __shfl_xor(rm2[r], msk, 64));
      rm3[r] = fminf(rm3[r], __shfl_xor(rm3[r], msk, 64));
    }

  int rowbase = dir * PTS + batch * N_ + rb * 512 + w * 128;
  float* gp = gpart + (size_t)q * ROWS_TOTAL + rowbase;
  if ((lane & 31) == 0) {                      // lanes 0 and 32 (h = lane>>5)
    int h = lane >> 5;
#pragma unroll
    for (int r = 0; r < 16; ++r) {
      int rr = (r & 3) + 8 * (r >> 2) + 4 * h;
      gp[0 * 32 + rr] = rm0[r];
      gp[1 * 32 + rr] = rm1[r];
      gp[2 * 32 + rr] = rm2[r];
      gp[3 * 32 + rr] = rm3[r];
    }
  }
}

// ---- dispatch 3: min the 4 candidate-quarter partials, sum everything ----
__global__ __launch_bounds__(256) void chamfer_final_k(
    const float* __restrict__ gpart, float* __restrict__ out) {
  int i = blockIdx.x * 256 + threadIdx.x;    // 32768 threads x 4 rows (float4)
  const float4* g4 = reinterpret_cast<const float4*>(gpart);
  float4 a = g4[i];
  float4 b = g4[i + (ROWS_TOTAL / 4)];
  float4 c = g4[i + 2 * (ROWS_TOTAL / 4)];
  float4 d = g4[i + 3 * (ROWS_TOTAL / 4)];
  float s = fminf(fminf(a.x, b.x), fminf(c.x, d.x))
          + fminf(fminf(a.y, b.y), fminf(c.y, d.y))
          + fminf(fminf(a.z, b.z), fminf(c.z, d.z))
          + fminf(fminf(a.w, b.w), fminf(c.w, d.w));
  for (int off = 32; off > 0; off >>= 1) s += __shfl_down(s, off, 64);
  __shared__ float red[4];
  int lane = threadIdx.x & 63, wv = threadIdx.x >> 6;
  if (lane == 0) red[wv] = s;
  __syncthreads();
  if (threadIdx.x == 0) {
    float tt = (red[0] + red[1]) + (red[2] + red[3]);
    atomicAdd(out, tt * (1.0f / (float)PTS));
  }
}

extern "C" void kernel_launch(void* const* d_in, const int* in_sizes, int n_in,
                              void* d_out, int out_size, void* d_ws, size_t ws_size,
                              hipStream_t stream) {
  const float* x = (const float*)d_in[0];
  const float* y = (const float*)d_in[1];
  float* out = (float*)d_out;
  // ws layout: gpart 2MB | afrag 4MB | bfrag 4MB  (10MB total)
  float* gpart = (float*)d_ws;
  uint4* afrag = (uint4*)((char*)d_ws + (size_t)4 * ROWS_TOTAL * sizeof(float));
  uint4* bfrag = afrag + (size_t)2 * NTILES * 64;

  pack_frags_k<<<1024, 256, 0, stream>>>(x, y, afrag, bfrag, out);
  chamfer_main_k<<<1024, TPB, 0, stream>>>(afrag, bfrag, gpart);
  chamfer_final_k<<<128, 256, 0, stream>>>(gpart, out);
}